// Round 5
// baseline (250.738 us; speedup 1.0000x reference)
//
#include <hip/hip_runtime.h>
#include <hip/hip_bf16.h>
#include <stdint.h>

// out[b,l,i,o] = sum_d head[b,i,d]*U[l,d]*dep[b,o,d] + t2h[b,l,i] + t2d[b,l,o] + b[l]
// B=16, S=256, D=768, L=32. out (16,32,256,256) fp32.
//
// R7: main K-step 64 (12 tiles): one lgkm-only barrier per 64 k (was 32),
// 64-MFMA cluster per barrier, 8 B-frag global loads in flight across each
// barrier. A LDS layout [kgrp(8)][row(128)][8] is naturally bank-balanced on
// both sides (swizzle dropped). MFMA accumulation order bit-identical to R5.
// prep unchanged from R6 (packed transpose-butterfly reduce).

#define B_ 16
#define S_ 256
#define D_ 768
#define L_ 32
#define KQ_ (D_ / 8)  // 96 groups of 8 d's
#define NT_ 12        // K-tiles of 64

typedef unsigned short ushort_t;
typedef __attribute__((ext_vector_type(4))) float f32x4;
typedef __attribute__((ext_vector_type(8))) short s16x8;

// round-half-up fp32->bf16 pair pack; f0 -> low half, f1 -> high half
__device__ __forceinline__ unsigned int pack_bf16(float f0, float f1) {
  unsigned int u0 = __builtin_bit_cast(unsigned int, f0) + 0x8000u;
  unsigned int u1 = __builtin_bit_cast(unsigned int, f1) + 0x8000u;
  return __builtin_amdgcn_perm(u1, u0, 0x07060302);
}

// ---------------------------------------------------------------------------
// Prep: one wave per 4 rows. Lane owns 12 d's in registers. t2 dots: per-lane
// FMA partials for 16 labels x 4 rows, then ONE packed transpose-butterfly
// (63 shuffles) delivers output j = l*4 + r to lane j. Two label-chunks.
// dep waves also emit bf16 depb in fragment-major layout
// depb[b][d>>3][col][d&7]. grid = 512 x 256 = 2048 waves = B*S*2/4 rows.
// ---------------------------------------------------------------------------
__global__ __launch_bounds__(256) void prep_kernel(
    const float* __restrict__ head, const float* __restrict__ dep,
    const float* __restrict__ labelW, ushort_t* __restrict__ depb,
    float* __restrict__ t2h, float* __restrict__ t2d) {
  const int wave = threadIdx.x >> 6;
  const int lane = threadIdx.x & 63;
  const int g = blockIdx.x * 4 + wave;  // 0..2047
  const int sel = g >> 10;              // 0=head, 1=dep
  const int idx = g & 1023;
  const int b = idx >> 6;
  const int row0 = (idx & 63) * 4;
  const float* src = sel ? dep : head;
  float* t2x = sel ? t2d : t2h;
  const int d0 = lane * 12;

  float h[4][12];
  const float* rp = src + ((size_t)(b * S_ + row0)) * D_ + d0;
#pragma unroll
  for (int r = 0; r < 4; ++r) {
    float4 v0 = *(const float4*)(rp + (size_t)r * D_);
    float4 v1 = *(const float4*)(rp + (size_t)r * D_ + 4);
    float4 v2 = *(const float4*)(rp + (size_t)r * D_ + 8);
    h[r][0] = v0.x; h[r][1] = v0.y; h[r][2] = v0.z; h[r][3] = v0.w;
    h[r][4] = v1.x; h[r][5] = v1.y; h[r][6] = v1.z; h[r][7] = v1.w;
    h[r][8] = v2.x; h[r][9] = v2.y; h[r][10] = v2.z; h[r][11] = v2.w;
  }
  if (sel) {
    // fragment-major: ushort off = ((b*96 + (d>>3))*256 + col)*8 + (d&7)
    const size_t bb = (size_t)b * (KQ_ * S_ * 8);
    const int m = lane >> 1;  // d0 = 24m (even lane) or 24m+12 (odd lane)
#pragma unroll
    for (int r = 0; r < 4; ++r) {
      const int col = row0 + r;
      unsigned int q0 = pack_bf16(h[r][0], h[r][1]);
      unsigned int q1 = pack_bf16(h[r][2], h[r][3]);
      unsigned int q2 = pack_bf16(h[r][4], h[r][5]);
      unsigned int q3 = pack_bf16(h[r][6], h[r][7]);
      unsigned int q4 = pack_bf16(h[r][8], h[r][9]);
      unsigned int q5 = pack_bf16(h[r][10], h[r][11]);
      if ((lane & 1) == 0) {
        uint4 a = {q0, q1, q2, q3};  // d0..d7 @ kq=3m
        uint2 c = {q4, q5};          // d8..d11 @ kq=3m+1, dlow 0..3
        *(uint4*)(depb + bb + ((size_t)(3 * m) * S_ + col) * 8) = a;
        *(uint2*)(depb + bb + ((size_t)(3 * m + 1) * S_ + col) * 8) = c;
      } else {
        uint2 c = {q0, q1};          // d0..d3 @ kq=3m+1, dlow 4..7
        uint4 a = {q2, q3, q4, q5};  // d4..d11 @ kq=3m+2
        *(uint2*)(depb + bb + ((size_t)(3 * m + 1) * S_ + col) * 8 + 4) = c;
        *(uint4*)(depb + bb + ((size_t)(3 * m + 2) * S_ + col) * 8) = a;
      }
    }
  }
  const float* wbase = labelW + sel * D_ + d0;
  // two chunks of 16 labels; v[j] = partial for output j = lq*4 + r
  for (int c = 0; c < 2; ++c) {
    float v[64];
#pragma unroll
    for (int j = 0; j < 64; ++j) v[j] = 0.f;
    const float* wc = wbase + (size_t)(c * 16) * (2 * D_);
#pragma unroll
    for (int lq = 0; lq < 16; ++lq) {
      const float* wp = wc + (size_t)lq * (2 * D_);
      float4 w0 = *(const float4*)(wp);
      float4 w1 = *(const float4*)(wp + 4);
      float4 w2 = *(const float4*)(wp + 8);
      float w[12] = {w0.x, w0.y, w0.z, w0.w, w1.x, w1.y, w1.z, w1.w,
                     w2.x, w2.y, w2.z, w2.w};
#pragma unroll
      for (int j = 0; j < 12; ++j) {
        v[lq * 4 + 0] += h[0][j] * w[j];
        v[lq * 4 + 1] += h[1][j] * w[j];
        v[lq * 4 + 2] += h[2][j] * w[j];
        v[lq * 4 + 3] += h[3][j] * w[j];
      }
    }
    // packed transpose-butterfly: combine order (own + partner, high bit
    // first) matches the old per-output allreduce bit-for-bit.
#pragma unroll
    for (int off = 32; off >= 1; off >>= 1) {
      const bool hi = (lane & off) != 0;
#pragma unroll
      for (int k = 0; k < 64; ++k) {
        if (k >= off) continue;  // live window is [0, off)
        float send = hi ? v[k] : v[k + off];
        float keep = hi ? v[k + off] : v[k];
        v[k] = keep + __shfl_xor(send, off);
      }
    }
    t2x[((size_t)(b * L_ + c * 16 + (lane >> 2))) * S_ + row0 + (lane & 3)] =
        v[0];
  }
}

// ---------------------------------------------------------------------------
// Main: block = (b, l, i-half). Tile 128(i) x 256(o), 4 waves of 128x64.
// grid = B*L*2 = 1024 blocks, 256 threads. K-step 64, double-buffered A LDS,
// one lgkm-only barrier per K-step; B direct-to-register, prefetched one
// full K-step ahead.
// ---------------------------------------------------------------------------
__global__ __launch_bounds__(256, 2) void main_kernel(
    const float* __restrict__ head, const ushort_t* __restrict__ depb,
    const float* __restrict__ U, const float* __restrict__ bias,
    const float* __restrict__ t2h, const float* __restrict__ t2d,
    float* __restrict__ out) {
  // A fragment-major [buf][kgrp(8)][row(128)][8] bf16; naturally
  // bank-balanced on both ds_write (kg=t&7, row=t>>3) and ds_read
  // (16-lane groups hit 8 distinct 16B starts).
  __shared__ __attribute__((aligned(16))) ushort_t As[2 * 8 * 128 * 8];  // 32 KB
  __shared__ float T2[384];  // [0:128]=t2h tile rows, [128:384]=t2d all cols

  // XCD-bijective swizzle: grid 1024 = 8 XCDs x 128 contiguous blocks (2 b's)
  const int hw = blockIdx.x;
  const int bid = ((hw & 7) << 7) | (hw >> 3);
  const int ic = bid & 1;
  const int bl = bid >> 1;
  const int l = bl & (L_ - 1);
  const int b = bl >> 5;
  const int ti = ic * 128;
  const int t = threadIdx.x;
  const int lane = t & 63;
  const int wave = t >> 6;

  for (int i = t; i < 384; i += 256)
    T2[i] = (i < 128) ? t2h[((size_t)(b * L_ + l)) * S_ + ti + i]
                      : t2d[((size_t)(b * L_ + l)) * S_ + (i - 128)];
  const float bv = bias[l];

  // A staging: thread t stages kgrp kg=t&7 for rows row0 + {0,32,64,96}
  const int row0 = t >> 3;  // 0..31
  const int kg = t & 7;     // 0..7
  const float* hp = head + ((size_t)(b * S_ + ti + row0)) * D_ + kg * 8;
  const float* Up = U + (size_t)l * D_ + kg * 8;
  const int awo = (kg * 128 + row0) * 8;  // +j*256 for row +32j

  // A frag reads: kgrp = h*4 + (lane>>4), row = rt*16 + (lane&15)
  const int aro = ((lane >> 4) * 128 + (lane & 15)) * 8;

  // B direct-from-global: wave owns cols [wave*64, wave*64+64)
  const ushort_t* dfb = depb + (size_t)b * (KQ_ * S_ * 8) +
                        ((size_t)((lane >> 4) * 256 + wave * 64 + (lane & 15))) * 8;

  f32x4 acc[8][4];
#pragma unroll
  for (int i = 0; i < 8; ++i)
#pragma unroll
    for (int j = 0; j < 4; ++j) acc[i][j] = {0.f, 0.f, 0.f, 0.f};

  s16x8 bfA[8], bfB[8];  // [h*4+ct] B frags for one 64-k tile

#define PACK_WRITE_A(BUF)                                                     \
  {                                                                           \
    ushort_t* aw = As + (BUF) * 8192 + awo;                                   \
    uint4 w;                                                                  \
    w.x = pack_bf16(h00.x * u0.x, h00.y * u0.y);                              \
    w.y = pack_bf16(h00.z * u0.z, h00.w * u0.w);                              \
    w.z = pack_bf16(h01.x * u1.x, h01.y * u1.y);                              \
    w.w = pack_bf16(h01.z * u1.z, h01.w * u1.w);                              \
    *(uint4*)(aw) = w;                                                        \
    w.x = pack_bf16(h10.x * u0.x, h10.y * u0.y);                              \
    w.y = pack_bf16(h10.z * u0.z, h10.w * u0.w);                              \
    w.z = pack_bf16(h11.x * u1.x, h11.y * u1.y);                              \
    w.w = pack_bf16(h11.z * u1.z, h11.w * u1.w);                              \
    *(uint4*)(aw + 256) = w;                                                  \
    w.x = pack_bf16(h20.x * u0.x, h20.y * u0.y);                              \
    w.y = pack_bf16(h20.z * u0.z, h20.w * u0.w);                              \
    w.z = pack_bf16(h21.x * u1.x, h21.y * u1.y);                              \
    w.w = pack_bf16(h21.z * u1.z, h21.w * u1.w);                              \
    *(uint4*)(aw + 512) = w;                                                  \
    w.x = pack_bf16(h30.x * u0.x, h30.y * u0.y);                              \
    w.y = pack_bf16(h30.z * u0.z, h30.w * u0.w);                              \
    w.z = pack_bf16(h31.x * u1.x, h31.y * u1.y);                              \
    w.w = pack_bf16(h31.z * u1.z, h31.w * u1.w);                              \
    *(uint4*)(aw + 768) = w;                                                  \
  }

#define LOAD_HU(tn)                                                           \
    const float* hq = hp + (tn) * 64;                                         \
    const float* uq = Up + (tn) * 64;                                         \
    float4 h00 = *(const float4*)(hq);                                        \
    float4 h01 = *(const float4*)(hq + 4);                                    \
    float4 h10 = *(const float4*)(hq + (size_t)32 * D_);                      \
    float4 h11 = *(const float4*)(hq + (size_t)32 * D_ + 4);                  \
    float4 h20 = *(const float4*)(hq + (size_t)64 * D_);                      \
    float4 h21 = *(const float4*)(hq + (size_t)64 * D_ + 4);                  \
    float4 h30 = *(const float4*)(hq + (size_t)96 * D_);                      \
    float4 h31 = *(const float4*)(hq + (size_t)96 * D_ + 4);                  \
    float4 u0 = *(const float4*)(uq);                                         \
    float4 u1 = *(const float4*)(uq + 4);

  // prologue: stage A(0) into buf 0; load bfA <- B tile 0
  {
    LOAD_HU(0)
    PACK_WRITE_A(0)
#pragma unroll
    for (int j = 0; j < 8; ++j)
      bfA[j] = *(const s16x8*)(dfb + (j >> 2) * 8192 + (j & 3) * 128);
  }
  asm volatile("s_waitcnt lgkmcnt(0)" ::: "memory");
  __builtin_amdgcn_s_barrier();
  __builtin_amdgcn_sched_barrier(0);

  // Per iteration (64-k tile tcur in buf PB): issue next tile's B-frag + h/u
  // loads (counted vmcnt, in flight across the barrier), 2 x (8 ds_read A
  // frags + 32 MFMA), pack+ds_write A(t+1) into PB^1, lgkm-only barrier.
#define ITER(PB, BFC, BFN, tcur)                                              \
  {                                                                           \
    int tn = (tcur) + 1;                                                      \
    if (tn == NT_) tn = 0; /* wrapped dummy prefetch keeps code uniform */    \
    const ushort_t* dfn = dfb + (size_t)tn * 16384;                           \
    _Pragma("unroll") for (int j = 0; j < 8; ++j)                             \
        BFN[j] = *(const s16x8*)(dfn + (j >> 2) * 8192 + (j & 3) * 128);      \
    LOAD_HU(tn)                                                               \
    __builtin_amdgcn_sched_barrier(0); /* pin load-issue cluster here */      \
    const ushort_t* arb = As + (PB) * 8192 + aro;                             \
    s16x8 af[8];                                                              \
    _Pragma("unroll") for (int rt = 0; rt < 8; ++rt)                          \
        af[rt] = *(const s16x8*)(arb + rt * 128);                             \
    __builtin_amdgcn_s_setprio(1);                                            \
    _Pragma("unroll") for (int rt = 0; rt < 8; ++rt)                          \
      _Pragma("unroll") for (int ct = 0; ct < 4; ++ct)                        \
          acc[rt][ct] = __builtin_amdgcn_mfma_f32_16x16x32_bf16(              \
              af[rt], BFC[ct], acc[rt][ct], 0, 0, 0);                         \
    __builtin_amdgcn_s_setprio(0);                                            \
    _Pragma("unroll") for (int rt = 0; rt < 8; ++rt)                          \
        af[rt] = *(const s16x8*)(arb + 4096 + rt * 128);                      \
    __builtin_amdgcn_s_setprio(1);                                            \
    _Pragma("unroll") for (int rt = 0; rt < 8; ++rt)                          \
      _Pragma("unroll") for (int ct = 0; ct < 4; ++ct)                        \
          acc[rt][ct] = __builtin_amdgcn_mfma_f32_16x16x32_bf16(              \
              af[rt], BFC[4 + ct], acc[rt][ct], 0, 0, 0);                     \
    __builtin_amdgcn_s_setprio(0);                                            \
    PACK_WRITE_A((PB) ^ 1)                                                    \
    asm volatile("s_waitcnt lgkmcnt(0)" ::: "memory");                        \
    __builtin_amdgcn_s_barrier();                                             \
    __builtin_amdgcn_sched_barrier(0);                                        \
  }

  for (int tt = 0; tt < NT_; tt += 2) {
    ITER(0, bfA, bfB, tt);
    ITER(1, bfB, bfA, tt + 1);
  }
#undef ITER
#undef LOAD_HU
#undef PACK_WRITE_A

  // epilogue: C/D layout col=lane&15, row=(lane>>4)*4+reg
  const int colg = lane & 15;
  const int rgrp = lane >> 4;
  float* ob = out + (((size_t)(b * L_ + l)) * S_ + ti) * S_;
#pragma unroll
  for (int rt = 0; rt < 8; ++rt) {
    const int r0 = rt * 16 + rgrp * 4;
#pragma unroll
    for (int ct = 0; ct < 4; ++ct) {
      const int c = wave * 64 + ct * 16 + colg;
      const float addc = T2[128 + c] + bv;
      float* p = ob + (size_t)r0 * S_ + c;
#pragma unroll
      for (int r = 0; r < 4; ++r)
        p[(size_t)r * S_] = acc[rt][ct][r] + T2[r0 + r] + addc;
    }
  }
}

extern "C" void kernel_launch(void* const* d_in, const int* in_sizes, int n_in,
                              void* d_out, int out_size, void* d_ws, size_t ws_size,
                              hipStream_t stream) {
  const float* head = (const float*)d_in[0];
  const float* dep = (const float*)d_in[1];
  const float* U = (const float*)d_in[2];
  const float* W = (const float*)d_in[3];
  const float* bias = (const float*)d_in[4];
  float* out = (float*)d_out;

  ushort_t* depb = (ushort_t*)d_ws;                              // 6,291,456 B
  float* t2h = (float*)((char*)d_ws + (size_t)B_ * S_ * D_ * 2);
  float* t2d = t2h + (size_t)B_ * L_ * S_;                       // 524,288 B each

  prep_kernel<<<512, 256, 0, stream>>>(head, dep, W, depb, t2h, t2d);
  main_kernel<<<B_ * L_ * 2, 256, 0, stream>>>(head, depb, U, bias, t2h, t2d, out);
}

// Round 6
// 232.852 us; speedup vs baseline: 1.0768x; 1.0768x over previous
//
#include <hip/hip_runtime.h>
#include <hip/hip_bf16.h>
#include <stdint.h>

// out[b,l,i,o] = sum_d head[b,i,d]*U[l,d]*dep[b,o,d] + t2h[b,l,i] + t2d[b,l,o] + b[l]
// B=16, S=256, D=768, L=32. out (16,32,256,256) fp32.
//
// R8: R5 schedule (swizzled A LDS double-buffer, one lgkm-only barrier per
// 32-k step, B direct-to-register one tile ahead, bit-identical accumulation
// order) with block tile halved to 128x128 (grid 2048, wave tile 64x64):
// ~155 VGPR/wave -> 3 blocks/CU (was 2) for +50% latency cover. setprio
// dropped (m190: negative in barrier-locked GEMM). prep unchanged from R6.

#define B_ 16
#define S_ 256
#define D_ 768
#define L_ 32
#define KQ_ (D_ / 8)  // 96 groups of 8 d's
#define NT_ 24        // K-tiles of 32

typedef unsigned short ushort_t;
typedef __attribute__((ext_vector_type(4))) float f32x4;
typedef __attribute__((ext_vector_type(8))) short s16x8;

// round-half-up fp32->bf16 pair pack; f0 -> low half, f1 -> high half
__device__ __forceinline__ unsigned int pack_bf16(float f0, float f1) {
  unsigned int u0 = __builtin_bit_cast(unsigned int, f0) + 0x8000u;
  unsigned int u1 = __builtin_bit_cast(unsigned int, f1) + 0x8000u;
  return __builtin_amdgcn_perm(u1, u0, 0x07060302);
}

// ---------------------------------------------------------------------------
// Prep: one wave per 4 rows. Lane owns 12 d's in registers. t2 dots: per-lane
// FMA partials for 16 labels x 4 rows, then ONE packed transpose-butterfly
// (63 shuffles) delivers output j = l*4 + r to lane j. Two label-chunks.
// dep waves also emit bf16 depb in fragment-major layout
// depb[b][d>>3][col][d&7]. grid = 512 x 256 = 2048 waves = B*S*2/4 rows.
// ---------------------------------------------------------------------------
__global__ __launch_bounds__(256) void prep_kernel(
    const float* __restrict__ head, const float* __restrict__ dep,
    const float* __restrict__ labelW, ushort_t* __restrict__ depb,
    float* __restrict__ t2h, float* __restrict__ t2d) {
  const int wave = threadIdx.x >> 6;
  const int lane = threadIdx.x & 63;
  const int g = blockIdx.x * 4 + wave;  // 0..2047
  const int sel = g >> 10;              // 0=head, 1=dep
  const int idx = g & 1023;
  const int b = idx >> 6;
  const int row0 = (idx & 63) * 4;
  const float* src = sel ? dep : head;
  float* t2x = sel ? t2d : t2h;
  const int d0 = lane * 12;

  float h[4][12];
  const float* rp = src + ((size_t)(b * S_ + row0)) * D_ + d0;
#pragma unroll
  for (int r = 0; r < 4; ++r) {
    float4 v0 = *(const float4*)(rp + (size_t)r * D_);
    float4 v1 = *(const float4*)(rp + (size_t)r * D_ + 4);
    float4 v2 = *(const float4*)(rp + (size_t)r * D_ + 8);
    h[r][0] = v0.x; h[r][1] = v0.y; h[r][2] = v0.z; h[r][3] = v0.w;
    h[r][4] = v1.x; h[r][5] = v1.y; h[r][6] = v1.z; h[r][7] = v1.w;
    h[r][8] = v2.x; h[r][9] = v2.y; h[r][10] = v2.z; h[r][11] = v2.w;
  }
  if (sel) {
    // fragment-major: ushort off = ((b*96 + (d>>3))*256 + col)*8 + (d&7)
    const size_t bb = (size_t)b * (KQ_ * S_ * 8);
    const int m = lane >> 1;  // d0 = 24m (even lane) or 24m+12 (odd lane)
#pragma unroll
    for (int r = 0; r < 4; ++r) {
      const int col = row0 + r;
      unsigned int q0 = pack_bf16(h[r][0], h[r][1]);
      unsigned int q1 = pack_bf16(h[r][2], h[r][3]);
      unsigned int q2 = pack_bf16(h[r][4], h[r][5]);
      unsigned int q3 = pack_bf16(h[r][6], h[r][7]);
      unsigned int q4 = pack_bf16(h[r][8], h[r][9]);
      unsigned int q5 = pack_bf16(h[r][10], h[r][11]);
      if ((lane & 1) == 0) {
        uint4 a = {q0, q1, q2, q3};  // d0..d7 @ kq=3m
        uint2 c = {q4, q5};          // d8..d11 @ kq=3m+1, dlow 0..3
        *(uint4*)(depb + bb + ((size_t)(3 * m) * S_ + col) * 8) = a;
        *(uint2*)(depb + bb + ((size_t)(3 * m + 1) * S_ + col) * 8) = c;
      } else {
        uint2 c = {q0, q1};          // d0..d3 @ kq=3m+1, dlow 4..7
        uint4 a = {q2, q3, q4, q5};  // d4..d11 @ kq=3m+2
        *(uint2*)(depb + bb + ((size_t)(3 * m + 1) * S_ + col) * 8 + 4) = c;
        *(uint4*)(depb + bb + ((size_t)(3 * m + 2) * S_ + col) * 8) = a;
      }
    }
  }
  const float* wbase = labelW + sel * D_ + d0;
  // two chunks of 16 labels; v[j] = partial for output j = lq*4 + r
  for (int c = 0; c < 2; ++c) {
    float v[64];
#pragma unroll
    for (int j = 0; j < 64; ++j) v[j] = 0.f;
    const float* wc = wbase + (size_t)(c * 16) * (2 * D_);
#pragma unroll
    for (int lq = 0; lq < 16; ++lq) {
      const float* wp = wc + (size_t)lq * (2 * D_);
      float4 w0 = *(const float4*)(wp);
      float4 w1 = *(const float4*)(wp + 4);
      float4 w2 = *(const float4*)(wp + 8);
      float w[12] = {w0.x, w0.y, w0.z, w0.w, w1.x, w1.y, w1.z, w1.w,
                     w2.x, w2.y, w2.z, w2.w};
#pragma unroll
      for (int j = 0; j < 12; ++j) {
        v[lq * 4 + 0] += h[0][j] * w[j];
        v[lq * 4 + 1] += h[1][j] * w[j];
        v[lq * 4 + 2] += h[2][j] * w[j];
        v[lq * 4 + 3] += h[3][j] * w[j];
      }
    }
    // packed transpose-butterfly: combine order (own + partner, high bit
    // first) matches the old per-output allreduce bit-for-bit.
#pragma unroll
    for (int off = 32; off >= 1; off >>= 1) {
      const bool hi = (lane & off) != 0;
#pragma unroll
      for (int k = 0; k < 64; ++k) {
        if (k >= off) continue;  // live window is [0, off)
        float send = hi ? v[k] : v[k + off];
        float keep = hi ? v[k + off] : v[k];
        v[k] = keep + __shfl_xor(send, off);
      }
    }
    t2x[((size_t)(b * L_ + c * 16 + (lane >> 2))) * S_ + row0 + (lane & 3)] =
        v[0];
  }
}

// ---------------------------------------------------------------------------
// Main: block = (b, l, i-half, o-half). Tile 128(i) x 128(o), 4 waves of
// 64x64 (2x2). grid = B*L*4 = 2048 blocks, 256 threads, 3 blocks/CU.
// ---------------------------------------------------------------------------

// XOR-swizzle on ushort offsets within an 8KB A buffer: kgrp (bits 11:10)
// into bits 5:4. Bijective; makes A ds_write (kg varies per lane) and
// ds_read (kg fixed per 16-lane group) both uniform 2/bank.
#define SWZ(o) ((o) ^ ((((o) >> 10) & 3) << 4))

__global__ __launch_bounds__(256, 3) void main_kernel(
    const float* __restrict__ head, const ushort_t* __restrict__ depb,
    const float* __restrict__ U, const float* __restrict__ bias,
    const float* __restrict__ t2h, const float* __restrict__ t2d,
    float* __restrict__ out) {
  // A fragment-major [buf][kgrp(4)][row(128)][8] bf16, XOR-swizzled
  __shared__ __attribute__((aligned(16))) ushort_t As[2 * 128 * 32];  // 16 KB
  __shared__ float T2[256];  // [0:128]=t2h tile rows, [128:256]=t2d tile cols

  // XCD-bijective swizzle: grid 2048 = 8 XCDs x 256 contiguous blocks (2 b's)
  const int hw = blockIdx.x;
  const int bid = ((hw & 7) << 8) | (hw >> 3);
  const int oh = bid & 1;
  const int ih = (bid >> 1) & 1;
  const int l = (bid >> 2) & (L_ - 1);
  const int b = bid >> 7;
  const int ti = ih * 128;  // row window
  const int to = oh * 128;  // col window
  const int t = threadIdx.x;
  const int lane = t & 63;
  const int wave = t >> 6;
  const int m_base = (wave >> 1) * 64;  // wave row offset in tile
  const int n_base = (wave & 1) * 64;   // wave col offset in tile

  for (int i = t; i < 256; i += 256)
    T2[i] = (i < 128) ? t2h[((size_t)(b * L_ + l)) * S_ + ti + i]
                      : t2d[((size_t)(b * L_ + l)) * S_ + to + (i - 128)];
  const float bv = bias[l];

  // A staging decomposition: thread t stages rows (t>>2, t>>2+64), kgrp t&3
  const int row0 = t >> 2;
  const int kg = t & 3;
  const float* hp0 = head + ((size_t)(b * S_ + ti + row0)) * D_ + kg * 8;
  const float* hp1 = hp0 + (size_t)64 * D_;
  const float* Up = U + (size_t)l * D_ + kg * 8;
  const int awo0s = SWZ((kg * 128 + row0) * 8);
  const int awo1s = awo0s + 512;  // +64 rows; doesn't touch swizzled bits

  // A frag reads: rows m_base + rt*16 + (lane&15), kgrp=lane>>4
  const int aros = SWZ(((lane >> 4) * 128 + m_base + (lane & 15)) * 8);

  // B direct-from-global: wave owns cols [to + n_base, +64)
  const ushort_t* dfb =
      depb + (size_t)b * (KQ_ * S_ * 8) +
      ((size_t)((lane >> 4) * 256 + to + n_base + (lane & 15))) * 8;

  f32x4 acc[4][4];
#pragma unroll
  for (int i = 0; i < 4; ++i)
#pragma unroll
    for (int j = 0; j < 4; ++j) acc[i][j] = {0.f, 0.f, 0.f, 0.f};

  s16x8 bfA[4], bfB[4];

  // prologue: stage A(0) into buf 0; load bfA <- B tile 0
  {
    float4 h0 = *(const float4*)(hp0);
    float4 h1 = *(const float4*)(hp0 + 4);
    float4 h2 = *(const float4*)(hp1);
    float4 h3 = *(const float4*)(hp1 + 4);
    float4 u0 = *(const float4*)(Up);
    float4 u1 = *(const float4*)(Up + 4);
    uint4 w0, w1;
    w0.x = pack_bf16(h0.x * u0.x, h0.y * u0.y);
    w0.y = pack_bf16(h0.z * u0.z, h0.w * u0.w);
    w0.z = pack_bf16(h1.x * u1.x, h1.y * u1.y);
    w0.w = pack_bf16(h1.z * u1.z, h1.w * u1.w);
    w1.x = pack_bf16(h2.x * u0.x, h2.y * u0.y);
    w1.y = pack_bf16(h2.z * u0.z, h2.w * u0.w);
    w1.z = pack_bf16(h3.x * u1.x, h3.y * u1.y);
    w1.w = pack_bf16(h3.z * u1.z, h3.w * u1.w);
    *(uint4*)(As + awo0s) = w0;
    *(uint4*)(As + awo1s) = w1;
#pragma unroll
    for (int ct = 0; ct < 4; ++ct)
      bfA[ct] = *(const s16x8*)(dfb + ct * 128);
  }
  asm volatile("s_waitcnt lgkmcnt(0)" ::: "memory");
  __builtin_amdgcn_s_barrier();
  __builtin_amdgcn_sched_barrier(0);

  // Per iteration (tile tcur, A in buf PB): issue next tile's h/u + B-frag
  // loads (compiler-counted vmcnt; in flight across the barrier), 4 ds_read
  // A frags, 16 MFMA, pack+ds_write A(t+1) into buf PB^1, lgkm-only barrier.
#define ITER(PB, BFC, BFN, tcur)                                              \
  {                                                                           \
    int tn = (tcur) + 1;                                                      \
    if (tn == NT_) tn = 0; /* wrapped dummy prefetch keeps code uniform */    \
    const float* hA = hp0 + tn * 32;                                          \
    const float* hB = hp1 + tn * 32;                                          \
    const float* uA = Up + tn * 32;                                           \
    float4 h0 = *(const float4*)(hA);                                         \
    float4 h1 = *(const float4*)(hA + 4);                                     \
    float4 h2 = *(const float4*)(hB);                                         \
    float4 h3 = *(const float4*)(hB + 4);                                     \
    float4 u0 = *(const float4*)(uA);                                         \
    float4 u1 = *(const float4*)(uA + 4);                                     \
    const ushort_t* dfn = dfb + (size_t)tn * 8192;                            \
    _Pragma("unroll") for (int ct = 0; ct < 4; ++ct)                          \
        BFN[ct] = *(const s16x8*)(dfn + ct * 128);                            \
    __builtin_amdgcn_sched_barrier(0); /* pin load-issue cluster here */      \
    s16x8 af[4];                                                              \
    _Pragma("unroll") for (int rt = 0; rt < 4; ++rt)                          \
        af[rt] = *(const s16x8*)(As + (PB)*4096 + aros + rt * 128);           \
    _Pragma("unroll") for (int rt = 0; rt < 4; ++rt)                          \
      _Pragma("unroll") for (int ct = 0; ct < 4; ++ct)                        \
          acc[rt][ct] = __builtin_amdgcn_mfma_f32_16x16x32_bf16(              \
              af[rt], BFC[ct], acc[rt][ct], 0, 0, 0);                         \
    uint4 w0, w1;                                                             \
    w0.x = pack_bf16(h0.x * u0.x, h0.y * u0.y);                               \
    w0.y = pack_bf16(h0.z * u0.z, h0.w * u0.w);                               \
    w0.z = pack_bf16(h1.x * u1.x, h1.y * u1.y);                               \
    w0.w = pack_bf16(h1.z * u1.z, h1.w * u1.w);                               \
    w1.x = pack_bf16(h2.x * u0.x, h2.y * u0.y);                               \
    w1.y = pack_bf16(h2.z * u0.z, h2.w * u0.w);                               \
    w1.z = pack_bf16(h3.x * u1.x, h3.y * u1.y);                               \
    w1.w = pack_bf16(h3.z * u1.z, h3.w * u1.w);                               \
    ushort_t* aw = As + ((PB) ^ 1) * 4096;                                    \
    *(uint4*)(aw + awo0s) = w0;                                               \
    *(uint4*)(aw + awo1s) = w1;                                               \
    asm volatile("s_waitcnt lgkmcnt(0)" ::: "memory");                        \
    __builtin_amdgcn_s_barrier();                                             \
    __builtin_amdgcn_sched_barrier(0);                                        \
  }

  for (int tt = 0; tt < NT_; tt += 2) {
    ITER(0, bfA, bfB, tt);
    ITER(1, bfB, bfA, tt + 1);
  }
#undef ITER

  // epilogue: C/D layout col=lane&15, row=(lane>>4)*4+reg
  const int colg = lane & 15;
  const int rgrp = lane >> 4;
  float* ob = out + (((size_t)(b * L_ + l)) * S_ + ti) * S_ + to;
#pragma unroll
  for (int rt = 0; rt < 4; ++rt) {
    const int r0 = m_base + rt * 16 + rgrp * 4;
#pragma unroll
    for (int ct = 0; ct < 4; ++ct) {
      const int c = n_base + ct * 16 + colg;
      const float addc = T2[128 + c] + bv;
      float* p = ob + (size_t)r0 * S_ + c;
#pragma unroll
      for (int r = 0; r < 4; ++r)
        p[(size_t)r * S_] = acc[rt][ct][r] + T2[r0 + r] + addc;
    }
  }
}

extern "C" void kernel_launch(void* const* d_in, const int* in_sizes, int n_in,
                              void* d_out, int out_size, void* d_ws, size_t ws_size,
                              hipStream_t stream) {
  const float* head = (const float*)d_in[0];
  const float* dep = (const float*)d_in[1];
  const float* U = (const float*)d_in[2];
  const float* W = (const float*)d_in[3];
  const float* bias = (const float*)d_in[4];
  float* out = (float*)d_out;

  ushort_t* depb = (ushort_t*)d_ws;                              // 6,291,456 B
  float* t2h = (float*)((char*)d_ws + (size_t)B_ * S_ * D_ * 2);
  float* t2d = t2h + (size_t)B_ * L_ * S_;                       // 524,288 B each

  prep_kernel<<<512, 256, 0, stream>>>(head, dep, W, depb, t2h, t2d);
  main_kernel<<<B_ * L_ * 4, 256, 0, stream>>>(head, depb, U, bias, t2h, t2d, out);
}

// Round 7
// 224.908 us; speedup vs baseline: 1.1148x; 1.0353x over previous
//
#include <hip/hip_runtime.h>
#include <hip/hip_bf16.h>
#include <stdint.h>

// out[b,l,i,o] = sum_d head[b,i,d]*U[l,d]*dep[b,o,d] + t2h[b,l,i] + t2d[b,l,o] + b[l]
// B=16, S=256, D=768, L=32. out (16,32,256,256) fp32.
//
// R9: main = 64(i) x 256(o) block tile, 4 waves of 64x64 (acc=64 VGPR),
// K-step 96 (8 barrier-iters of 3 k32-phases). Per phase: issue next-phase
// B-frags + one h/u staging chunk, 4 ds_read af, 16 MFMA, pack+ds_write the
// chunk to buf^1. One lgkm-only barrier per 96 k. Swizzled A LDS (2-way free
// on both sides). launch_bounds(256,3) -> 12 waves/CU. Accumulation order
// bit-identical to R5/R6. prep unchanged from R6.

#define B_ 16
#define S_ 256
#define D_ 768
#define L_ 32
#define KQ_ (D_ / 8)  // 96 groups of 8 d's
#define NT_ 8         // K-tiles of 96
#define NKT_ 24       // k32 chunks total

typedef unsigned short ushort_t;
typedef __attribute__((ext_vector_type(4))) float f32x4;
typedef __attribute__((ext_vector_type(8))) short s16x8;

// round-half-up fp32->bf16 pair pack; f0 -> low half, f1 -> high half
__device__ __forceinline__ unsigned int pack_bf16(float f0, float f1) {
  unsigned int u0 = __builtin_bit_cast(unsigned int, f0) + 0x8000u;
  unsigned int u1 = __builtin_bit_cast(unsigned int, f1) + 0x8000u;
  return __builtin_amdgcn_perm(u1, u0, 0x07060302);
}

// ---------------------------------------------------------------------------
// Prep: one wave per 4 rows. Lane owns 12 d's in registers. t2 dots: per-lane
// FMA partials for 16 labels x 4 rows, then ONE packed transpose-butterfly
// (63 shuffles) delivers output j = l*4 + r to lane j. Two label-chunks.
// dep waves also emit bf16 depb in fragment-major layout
// depb[b][d>>3][col][d&7]. grid = 512 x 256 = 2048 waves = B*S*2/4 rows.
// ---------------------------------------------------------------------------
__global__ __launch_bounds__(256) void prep_kernel(
    const float* __restrict__ head, const float* __restrict__ dep,
    const float* __restrict__ labelW, ushort_t* __restrict__ depb,
    float* __restrict__ t2h, float* __restrict__ t2d) {
  const int wave = threadIdx.x >> 6;
  const int lane = threadIdx.x & 63;
  const int g = blockIdx.x * 4 + wave;  // 0..2047
  const int sel = g >> 10;              // 0=head, 1=dep
  const int idx = g & 1023;
  const int b = idx >> 6;
  const int row0 = (idx & 63) * 4;
  const float* src = sel ? dep : head;
  float* t2x = sel ? t2d : t2h;
  const int d0 = lane * 12;

  float h[4][12];
  const float* rp = src + ((size_t)(b * S_ + row0)) * D_ + d0;
#pragma unroll
  for (int r = 0; r < 4; ++r) {
    float4 v0 = *(const float4*)(rp + (size_t)r * D_);
    float4 v1 = *(const float4*)(rp + (size_t)r * D_ + 4);
    float4 v2 = *(const float4*)(rp + (size_t)r * D_ + 8);
    h[r][0] = v0.x; h[r][1] = v0.y; h[r][2] = v0.z; h[r][3] = v0.w;
    h[r][4] = v1.x; h[r][5] = v1.y; h[r][6] = v1.z; h[r][7] = v1.w;
    h[r][8] = v2.x; h[r][9] = v2.y; h[r][10] = v2.z; h[r][11] = v2.w;
  }
  if (sel) {
    // fragment-major: ushort off = ((b*96 + (d>>3))*256 + col)*8 + (d&7)
    const size_t bb = (size_t)b * (KQ_ * S_ * 8);
    const int m = lane >> 1;  // d0 = 24m (even lane) or 24m+12 (odd lane)
#pragma unroll
    for (int r = 0; r < 4; ++r) {
      const int col = row0 + r;
      unsigned int q0 = pack_bf16(h[r][0], h[r][1]);
      unsigned int q1 = pack_bf16(h[r][2], h[r][3]);
      unsigned int q2 = pack_bf16(h[r][4], h[r][5]);
      unsigned int q3 = pack_bf16(h[r][6], h[r][7]);
      unsigned int q4 = pack_bf16(h[r][8], h[r][9]);
      unsigned int q5 = pack_bf16(h[r][10], h[r][11]);
      if ((lane & 1) == 0) {
        uint4 a = {q0, q1, q2, q3};  // d0..d7 @ kq=3m
        uint2 c = {q4, q5};          // d8..d11 @ kq=3m+1, dlow 0..3
        *(uint4*)(depb + bb + ((size_t)(3 * m) * S_ + col) * 8) = a;
        *(uint2*)(depb + bb + ((size_t)(3 * m + 1) * S_ + col) * 8) = c;
      } else {
        uint2 c = {q0, q1};          // d0..d3 @ kq=3m+1, dlow 4..7
        uint4 a = {q2, q3, q4, q5};  // d4..d11 @ kq=3m+2
        *(uint2*)(depb + bb + ((size_t)(3 * m + 1) * S_ + col) * 8 + 4) = c;
        *(uint4*)(depb + bb + ((size_t)(3 * m + 2) * S_ + col) * 8) = a;
      }
    }
  }
  const float* wbase = labelW + sel * D_ + d0;
  // two chunks of 16 labels; v[j] = partial for output j = lq*4 + r
  for (int c = 0; c < 2; ++c) {
    float v[64];
#pragma unroll
    for (int j = 0; j < 64; ++j) v[j] = 0.f;
    const float* wc = wbase + (size_t)(c * 16) * (2 * D_);
#pragma unroll
    for (int lq = 0; lq < 16; ++lq) {
      const float* wp = wc + (size_t)lq * (2 * D_);
      float4 w0 = *(const float4*)(wp);
      float4 w1 = *(const float4*)(wp + 4);
      float4 w2 = *(const float4*)(wp + 8);
      float w[12] = {w0.x, w0.y, w0.z, w0.w, w1.x, w1.y, w1.z, w1.w,
                     w2.x, w2.y, w2.z, w2.w};
#pragma unroll
      for (int j = 0; j < 12; ++j) {
        v[lq * 4 + 0] += h[0][j] * w[j];
        v[lq * 4 + 1] += h[1][j] * w[j];
        v[lq * 4 + 2] += h[2][j] * w[j];
        v[lq * 4 + 3] += h[3][j] * w[j];
      }
    }
    // packed transpose-butterfly: combine order (own + partner, high bit
    // first) matches the old per-output allreduce bit-for-bit.
#pragma unroll
    for (int off = 32; off >= 1; off >>= 1) {
      const bool hi = (lane & off) != 0;
#pragma unroll
      for (int k = 0; k < 64; ++k) {
        if (k >= off) continue;  // live window is [0, off)
        float send = hi ? v[k] : v[k + off];
        float keep = hi ? v[k + off] : v[k];
        v[k] = keep + __shfl_xor(send, off);
      }
    }
    t2x[((size_t)(b * L_ + c * 16 + (lane >> 2))) * S_ + row0 + (lane & 3)] =
        v[0];
  }
}

// ---------------------------------------------------------------------------
// Main: block = (b, l, row-quarter). Tile 64(i) x 256(o), 4 waves of 64x64.
// grid = B*L*4 = 2048 blocks, 256 threads, 3 waves/SIMD.
// ---------------------------------------------------------------------------

// A LDS: per 96-k buffer = 3 phase sub-buffers of [kg(4)][row(64)][8] bf16
// (2048 ushorts = 4KB each). Swizzle: kg (ushort-offset bits 10:9) XORed
// into bits 5:4 -> uniform 2-way (free) on both ds_write and ds_read.
#define SWZ(o) ((o) ^ ((((o) >> 9) & 3) << 4))

__global__ __launch_bounds__(256, 3) void main_kernel(
    const float* __restrict__ head, const ushort_t* __restrict__ depb,
    const float* __restrict__ U, const float* __restrict__ bias,
    const float* __restrict__ t2h, const float* __restrict__ t2d,
    float* __restrict__ out) {
  __shared__ __attribute__((aligned(16))) ushort_t As[2 * 3 * 2048];  // 24 KB
  __shared__ float T2[320];  // [0:64]=t2h tile rows, [64:320]=t2d all cols

  // XCD-bijective swizzle: grid 2048 = 8 XCDs x 256 contiguous blocks (2 b's)
  const int hw = blockIdx.x;
  const int bid = ((hw & 7) << 8) | (hw >> 3);
  const int rq = bid & 3;             // row quarter
  const int l = (bid >> 2) & (L_ - 1);
  const int b = bid >> 7;
  const int ti = rq * 64;
  const int t = threadIdx.x;
  const int lane = t & 63;
  const int wave = t >> 6;

  for (int i = t; i < 320; i += 256)
    T2[i] = (i < 64) ? t2h[((size_t)(b * L_ + l)) * S_ + ti + i]
                     : t2d[((size_t)(b * L_ + l)) * S_ + (i - 64)];
  const float bv = bias[l];

  // A staging: thread t stages row row0=t>>2 (0..63), kgrp kg=t&3 per chunk
  const int row0 = t >> 2;
  const int kg = t & 3;
  const float* hp = head + ((size_t)(b * S_ + ti + row0)) * D_ + kg * 8;
  const float* Up = U + (size_t)l * D_ + kg * 8;
  const int awos = SWZ((kg * 64 + row0) * 8);

  // A frag reads: kgrp = lane>>4, row = rt*16 + (lane&15)
  const int aros = SWZ(((lane >> 4) * 64 + (lane & 15)) * 8);

  // B direct-from-global: wave owns cols [wave*64, wave*64+64)
  const ushort_t* dfb =
      depb + (size_t)b * (KQ_ * S_ * 8) +
      ((size_t)((lane >> 4) * 256 + wave * 64 + (lane & 15))) * 8;

  f32x4 acc[4][4];
#pragma unroll
  for (int i = 0; i < 4; ++i)
#pragma unroll
    for (int j = 0; j < 4; ++j) acc[i][j] = {0.f, 0.f, 0.f, 0.f};

  s16x8 bfA[4], bfB[4];

#define PACK_WRITE_CH(BUF, PH)                                                \
  {                                                                           \
    uint4 w;                                                                  \
    w.x = pack_bf16(hh0.x * uu0.x, hh0.y * uu0.y);                            \
    w.y = pack_bf16(hh0.z * uu0.z, hh0.w * uu0.w);                            \
    w.z = pack_bf16(hh1.x * uu1.x, hh1.y * uu1.y);                            \
    w.w = pack_bf16(hh1.z * uu1.z, hh1.w * uu1.w);                            \
    *(uint4*)(As + (BUF)*6144 + (PH)*2048 + awos) = w;                        \
  }

  // prologue: stage all 3 chunks of tile 0 into buf 0; load bfA <- chunk 0
  {
#pragma unroll
    for (int c = 0; c < 3; ++c) {
      float4 hh0 = *(const float4*)(hp + c * 32);
      float4 hh1 = *(const float4*)(hp + c * 32 + 4);
      float4 uu0 = *(const float4*)(Up + c * 32);
      float4 uu1 = *(const float4*)(Up + c * 32 + 4);
      PACK_WRITE_CH(0, c)
    }
#pragma unroll
    for (int ct = 0; ct < 4; ++ct)
      bfA[ct] = *(const s16x8*)(dfb + ct * 128);
  }
  asm volatile("s_waitcnt lgkmcnt(0)" ::: "memory");
  __builtin_amdgcn_s_barrier();
  __builtin_amdgcn_sched_barrier(0);

  // Phase (k32 chunk kt = tcur*3+PH): issue B frags for chunk kt+1 into BFN,
  // issue h/u for chunk PH of tile tcur+1 (global chunk kt+3), 4 ds_read af
  // from buf PB phase PH, 16 MFMA with BFC, pack+ds_write the h/u chunk into
  // buf PB^1 phase PH. Loads stay in flight across phases (counted vmcnt).
#define PHASE(PB, PH, BFC, BFN, tcur)                                         \
  {                                                                           \
    const int kt = (tcur)*3 + (PH);                                           \
    int ktn = kt + 1;                                                         \
    if (ktn == NKT_) ktn = 0; /* wrapped dummy keeps code uniform */          \
    int ku = kt + 3;                                                          \
    if (ku >= NKT_) ku -= NKT_;                                               \
    const ushort_t* dfn = dfb + (size_t)ktn * 8192;                           \
    _Pragma("unroll") for (int ct = 0; ct < 4; ++ct)                          \
        BFN[ct] = *(const s16x8*)(dfn + ct * 128);                            \
    float4 hh0 = *(const float4*)(hp + ku * 32);                              \
    float4 hh1 = *(const float4*)(hp + ku * 32 + 4);                          \
    float4 uu0 = *(const float4*)(Up + ku * 32);                              \
    float4 uu1 = *(const float4*)(Up + ku * 32 + 4);                          \
    __builtin_amdgcn_sched_barrier(0); /* pin load-issue cluster here */      \
    const ushort_t* arb = As + (PB)*6144 + (PH)*2048 + aros;                  \
    s16x8 af[4];                                                              \
    _Pragma("unroll") for (int rt = 0; rt < 4; ++rt)                          \
        af[rt] = *(const s16x8*)(arb + rt * 128);                             \
    _Pragma("unroll") for (int rt = 0; rt < 4; ++rt)                          \
      _Pragma("unroll") for (int ct = 0; ct < 4; ++ct)                        \
          acc[rt][ct] = __builtin_amdgcn_mfma_f32_16x16x32_bf16(              \
              af[rt], BFC[ct], acc[rt][ct], 0, 0, 0);                         \
    PACK_WRITE_CH((PB) ^ 1, PH)                                               \
  }

#define ITER(PB, BFX, BFY, tcur)                                              \
  {                                                                           \
    PHASE(PB, 0, BFX, BFY, tcur)                                              \
    PHASE(PB, 1, BFY, BFX, tcur)                                              \
    PHASE(PB, 2, BFX, BFY, tcur)                                              \
    asm volatile("s_waitcnt lgkmcnt(0)" ::: "memory");                        \
    __builtin_amdgcn_s_barrier();                                             \
    __builtin_amdgcn_sched_barrier(0);                                        \
  }

  for (int tt = 0; tt < NT_; tt += 2) {
    ITER(0, bfA, bfB, tt);
    ITER(1, bfB, bfA, tt + 1);
  }
#undef ITER
#undef PHASE
#undef PACK_WRITE_CH

  // epilogue: C/D layout col=lane&15, row=(lane>>4)*4+reg
  const int colg = lane & 15;
  const int rgrp = lane >> 4;
  float* ob = out + (((size_t)(b * L_ + l)) * S_ + ti) * S_;
#pragma unroll
  for (int rt = 0; rt < 4; ++rt) {
    const int r0 = rt * 16 + rgrp * 4;
#pragma unroll
    for (int ct = 0; ct < 4; ++ct) {
      const int c = wave * 64 + ct * 16 + colg;
      const float addc = T2[64 + c] + bv;
      float* p = ob + (size_t)r0 * S_ + c;
#pragma unroll
      for (int r = 0; r < 4; ++r)
        p[(size_t)r * S_] = acc[rt][ct][r] + T2[r0 + r] + addc;
    }
  }
}

extern "C" void kernel_launch(void* const* d_in, const int* in_sizes, int n_in,
                              void* d_out, int out_size, void* d_ws, size_t ws_size,
                              hipStream_t stream) {
  const float* head = (const float*)d_in[0];
  const float* dep = (const float*)d_in[1];
  const float* U = (const float*)d_in[2];
  const float* W = (const float*)d_in[3];
  const float* bias = (const float*)d_in[4];
  float* out = (float*)d_out;

  ushort_t* depb = (ushort_t*)d_ws;                              // 6,291,456 B
  float* t2h = (float*)((char*)d_ws + (size_t)B_ * S_ * D_ * 2);
  float* t2d = t2h + (size_t)B_ * L_ * S_;                       // 524,288 B each

  prep_kernel<<<512, 256, 0, stream>>>(head, dep, W, depb, t2h, t2d);
  main_kernel<<<B_ * L_ * 4, 256, 0, stream>>>(head, depb, U, bias, t2h, t2d, out);
}